// Round 7
// baseline (355.291 us; speedup 1.0000x reference)
//
#include <hip/hip_runtime.h>
#include <hip/hip_cooperative_groups.h>
#include <math.h>

namespace cg = cooperative_groups;

#define N_ROWS 8192
#define D_DIM  512
#define C_CLS  100
#define GRID   256

typedef unsigned short u16;
typedef unsigned int u32;
typedef __attribute__((ext_vector_type(8))) short short8;
typedef __attribute__((ext_vector_type(4))) float floatx4;

// ---------------- ws layout (float offsets), ~28.9 MB ----------------
#define WS_G      0              // 512*512
#define WS_GP     262144         // 16 * 10 * 128*128 upper-tile partials
#define WS_INV    2883584        // 8192
#define WS_SINV   2891776        // 8192
#define WS_WV     2899968        // 8192
#define WS_CLS    2908160        // 8192 (int)
#define WS_CNT    2916352        // 128 (int)
#define WS_OFFS   2916480        // 128 (int)
#define WS_ORDER  2916608        // 8192 (int)
#define WS_ZTH    2924800        // 512*8192 u16
#define WS_ZTL    5021952
#define WS_U      7119104        // 100*512
#define WS_V      7170304        // 100*512

#define LDT 65

struct SMem {
    union {
        struct { u16 Ah[128*32], Al[128*32], Bh[128*32], Bl[128*32]; } g; // 32 KB
        unsigned zt_p[64 * LDT];
        struct { int hist[128], scan[128], cur[128]; } s;
        struct { float us[4][64], vs[4][64]; } uv;
        float ug[D_DIM];
    };
};

// split fp32 -> bf16 hi (chop) + bf16 lo (chop of remainder); rel err ~2^-16
__device__ __forceinline__ void split2(float v, u16& h, u16& l) {
    unsigned u = __float_as_uint(v);
    h = (u16)(u >> 16);
    float r = v - __uint_as_float(u & 0xFFFF0000u);
    l = (u16)(__float_as_uint(r) >> 16);
}

typedef const __attribute__((address_space(1))) u32* gp32;
typedef __attribute__((address_space(3))) u32* lp32;
__device__ __forceinline__ void cp16(const u16* g, u16* l) {
    __builtin_amdgcn_global_load_lds((gp32)g, (lp32)l, 16, 0, 0);
}

// ================= P1: softmax stats + row norms (wave per row) =======
__device__ void phase_prep(int bx, int t, const float* __restrict__ logits,
        const float* __restrict__ x, float* __restrict__ wv,
        int* __restrict__ cls, float* __restrict__ inv, float* __restrict__ sinv) {
    int gwave = (bx << 2) + (t >> 6);          // 0..1023
    int lane = t & 63;
    for (int row = gwave; row < N_ROWS; row += 1024) {
        const float* lrow = logits + (size_t)row * C_CLS;
        float v1 = lrow[lane];
        bool has2 = (lane + 64) < C_CLS;
        float v2 = has2 ? lrow[lane + 64] : -INFINITY;
        float m; int idx;
        if (v2 > v1) { m = v2; idx = lane + 64; } else { m = v1; idx = lane; }
        #pragma unroll
        for (int off = 32; off >= 1; off >>= 1) {
            float om = __shfl_down(m, off);
            int   oi = __shfl_down(idx, off);
            if (om > m || (om == m && oi < idx)) { m = om; idx = oi; }
        }
        m = __shfl(m, 0);
        idx = __shfl(idx, 0);
        float s = expf(v1 - m) + (has2 ? expf(v2 - m) : 0.0f);
        #pragma unroll
        for (int off = 32; off >= 1; off >>= 1) s += __shfl_down(s, off);
        const float* xr = x + (size_t)row * D_DIM;
        float ss = 0.f;
        #pragma unroll
        for (int j = 0; j < D_DIM; j += 64) {
            float v = xr[j + lane];
            ss += v * v;
        }
        #pragma unroll
        for (int off = 32; off >= 1; off >>= 1) ss += __shfl_down(ss, off);
        if (lane == 0) {
            wv[row] = 1.0f / s;
            cls[row] = idx;
            float iv = 1.0f / fmaxf(sqrtf(ss), 1e-8f);
            inv[row] = iv;
            sinv[row] = sqrtf(iv);
        }
    }
}

// ======== P2: last block = class sort; others = z split+transpose ======
__device__ void phase_mid(SMem& sm, int bx, int t, const float* __restrict__ x,
        const float* __restrict__ sinv, const int* __restrict__ cls,
        u16* __restrict__ zth, u16* __restrict__ ztl,
        int* __restrict__ cnt, int* __restrict__ offs, int* __restrict__ order) {
    if (bx == GRID - 1) {
        if (t < 128) sm.s.hist[t] = 0;
        __syncthreads();
        for (int m2 = t; m2 < N_ROWS; m2 += 256) atomicAdd(&sm.s.hist[cls[m2]], 1);
        __syncthreads();
        if (t < 128) sm.s.scan[t] = sm.s.hist[t];
        __syncthreads();
        #pragma unroll
        for (int d = 1; d < 128; d <<= 1) {
            int add = (t < 128 && t >= d) ? sm.s.scan[t - d] : 0;
            __syncthreads();
            if (t < 128) sm.s.scan[t] += add;
            __syncthreads();
        }
        if (t < 128) {
            int off0 = sm.s.scan[t] - sm.s.hist[t];
            sm.s.cur[t] = off0;
            offs[t] = off0;
            cnt[t] = sm.s.hist[t];
        }
        __syncthreads();
        for (int m2 = t; m2 < N_ROWS; m2 += 256) {
            int p = atomicAdd(&sm.s.cur[cls[m2]], 1);
            order[p] = m2;
        }
        return;
    }
    for (int tile = bx; tile < 1024; tile += (GRID - 1)) {
        int r0 = (tile & 127) << 6, c0 = (tile >> 7) << 6;
        int r = t >> 2, cq = t & 3;
        const float* src = x + (size_t)(r0 + r) * D_DIM + c0 + cq * 16;
        float vv[16];
        {
            float4 a = *(const float4*)(src + 0);
            float4 b = *(const float4*)(src + 4);
            float4 c = *(const float4*)(src + 8);
            float4 d = *(const float4*)(src + 12);
            vv[0]=a.x; vv[1]=a.y; vv[2]=a.z; vv[3]=a.w;
            vv[4]=b.x; vv[5]=b.y; vv[6]=b.z; vv[7]=b.w;
            vv[8]=c.x; vv[9]=c.y; vv[10]=c.z; vv[11]=c.w;
            vv[12]=d.x; vv[13]=d.y; vv[14]=d.z; vv[15]=d.w;
        }
        float sv = sinv[r0 + r];
        #pragma unroll
        for (int j = 0; j < 16; ++j) {
            u16 h, l;
            split2(sv * vv[j], h, l);
            sm.zt_p[(cq * 16 + j) * LDT + r] = ((unsigned)h << 16) | l;
        }
        __syncthreads();
        int c = t >> 2, rq = (t & 3) * 16;
        size_t tbase = (size_t)(c0 + c) * N_ROWS + r0 + rq;
        uint oh[8], ol[8];
        #pragma unroll
        for (int p = 0; p < 8; ++p) {
            unsigned d0 = sm.zt_p[c * LDT + rq + 2*p];
            unsigned d1 = sm.zt_p[c * LDT + rq + 2*p + 1];
            oh[p] = (d0 >> 16) | (d1 & 0xFFFF0000u);
            ol[p] = (d0 & 0xFFFFu) | (d1 << 16);
        }
        *(uint4*)&zth[tbase]     = make_uint4(oh[0], oh[1], oh[2], oh[3]);
        *(uint4*)&zth[tbase + 8] = make_uint4(oh[4], oh[5], oh[6], oh[7]);
        *(uint4*)&ztl[tbase]     = make_uint4(ol[0], ol[1], ol[2], ol[3]);
        *(uint4*)&ztl[tbase + 8] = make_uint4(ol[4], ol[5], ol[6], ol[7]);
        __syncthreads();
    }
}

// ====== P3: blocks 0..159 GEMM upper tiles (splitK=16); rest = uv ======
__device__ void phase_big(SMem& sm, int bx, int t, const u16* __restrict__ zth,
        const u16* __restrict__ ztl, const float* __restrict__ x,
        const float* __restrict__ inv, const float* __restrict__ wv,
        const int* __restrict__ order, const int* __restrict__ offs,
        const int* __restrict__ cnt, float* __restrict__ Gp,
        float* __restrict__ u_arr, float* __restrict__ v_arr) {
    if (bx < 160) {
        int tile = bx % 10;
        int p = bx / 10;                    // 0..15
        int ti = tile < 4 ? 0 : (tile < 7 ? 1 : (tile < 9 ? 2 : 3));
        int tj = tile - (ti == 0 ? 0 : (ti == 1 ? 3 : (ti == 2 ? 5 : 6)));
        int i0 = ti << 7, j0 = tj << 7;
        bool diag = (ti == tj);
        int kb = p << 9;                    // K-chunk of 512
        int w = t >> 6, l = t & 63;
        int srow = t >> 2, scol = (t & 3) << 3;
        int lm = l & 15, lg = l >> 4;
        floatx4 acc[4][4];
        #pragma unroll
        for (int mi = 0; mi < 4; ++mi)
            #pragma unroll
            for (int ni = 0; ni < 4; ++ni) acc[mi][ni] = (floatx4){0.f,0.f,0.f,0.f};
        int d0 = srow * 32 + scol;
        int d1 = (64 + srow) * 32 + scol;
        const size_t ga0 = (size_t)(i0 + srow) * N_ROWS + kb + scol;
        const size_t ga1 = (size_t)(i0 + 64 + srow) * N_ROWS + kb + scol;
        const size_t gb0 = (size_t)(j0 + srow) * N_ROWS + kb + scol;
        const size_t gb1 = (size_t)(j0 + 64 + srow) * N_ROWS + kb + scol;
        const u16* Bhs = diag ? sm.g.Ah : sm.g.Bh;
        const u16* Bls = diag ? sm.g.Al : sm.g.Bl;
        for (int s = 0; s < 16; ++s) {
            int ks = s << 5;
            cp16(zth + ga0 + ks, sm.g.Ah + d0);
            cp16(zth + ga1 + ks, sm.g.Ah + d1);
            cp16(ztl + ga0 + ks, sm.g.Al + d0);
            cp16(ztl + ga1 + ks, sm.g.Al + d1);
            if (!diag) {
                cp16(zth + gb0 + ks, sm.g.Bh + d0);
                cp16(zth + gb1 + ks, sm.g.Bh + d1);
                cp16(ztl + gb0 + ks, sm.g.Bl + d0);
                cp16(ztl + gb1 + ks, sm.g.Bl + d1);
            }
            __syncthreads();
            short8 ah[4], al[4], bh[4], bl[4];
            #pragma unroll
            for (int mi = 0; mi < 4; ++mi) {
                int off = (((w & 1) << 6) + (mi << 4) + lm) * 32 + (lg << 3);
                ah[mi] = *(const short8*)&sm.g.Ah[off];
                al[mi] = *(const short8*)&sm.g.Al[off];
            }
            #pragma unroll
            for (int ni = 0; ni < 4; ++ni) {
                int off = (((w >> 1) << 6) + (ni << 4) + lm) * 32 + (lg << 3);
                bh[ni] = *(const short8*)&Bhs[off];
                bl[ni] = *(const short8*)&Bls[off];
            }
            #pragma unroll
            for (int mi = 0; mi < 4; ++mi)
                #pragma unroll
                for (int ni = 0; ni < 4; ++ni) {
                    acc[mi][ni] = __builtin_amdgcn_mfma_f32_16x16x32_bf16(ah[mi], bh[ni], acc[mi][ni], 0, 0, 0);
                    acc[mi][ni] = __builtin_amdgcn_mfma_f32_16x16x32_bf16(ah[mi], bl[ni], acc[mi][ni], 0, 0, 0);
                    acc[mi][ni] = __builtin_amdgcn_mfma_f32_16x16x32_bf16(al[mi], bh[ni], acc[mi][ni], 0, 0, 0);
                }
            __syncthreads();
        }
        float* Gb = Gp + ((size_t)(p * 10 + tile) << 14);
        #pragma unroll
        for (int mi = 0; mi < 4; ++mi) {
            int row0 = ((w & 1) << 6) + (mi << 4) + (lg << 2);
            #pragma unroll
            for (int ni = 0; ni < 4; ++ni) {
                int col = ((w >> 1) << 6) + (ni << 4) + lm;
                #pragma unroll
                for (int r = 0; r < 4; ++r)
                    Gb[(size_t)(row0 + r) * 128 + col] = acc[mi][ni][r];
            }
        }
    } else {
        for (int idx = bx - 160; idx < 800; idx += (GRID - 160)) {
            int c = idx >> 3, jc = idx & 7;
            int g = t >> 6, lane = t & 63;
            int j = jc * 64 + lane;
            int n = cnt[c], o = offs[c];
            float ua = 0.f, va = 0.f;
            for (int p = g; p < n; p += 4) {
                int m = order[o + p];
                float wm = wv[m];
                float wi = wm * inv[m];
                float xv = x[(size_t)m * D_DIM + j];
                ua += wi * xv; va += wm * xv;
            }
            sm.uv.us[g][lane] = ua; sm.uv.vs[g][lane] = va;
            __syncthreads();
            if (g == 0) {
                u_arr[(size_t)c * D_DIM + j] = sm.uv.us[0][lane] + sm.uv.us[1][lane] + sm.uv.us[2][lane] + sm.uv.us[3][lane];
                v_arr[(size_t)c * D_DIM + j] = sm.uv.vs[0][lane] + sm.uv.vs[1][lane] + sm.uv.vs[2][lane] + sm.uv.vs[3][lane];
            }
            __syncthreads();
        }
    }
}

// ========= P4: G full = reduce 16 partials (mirror lower tri) ==========
__device__ void phase_reduceG(int bx, int t, const float* __restrict__ Gp,
                              float* __restrict__ G) {
    int base = bx * 256 + t;               // 0..65535
    #pragma unroll
    for (int q = 0; q < 4; ++q) {
        int i = base + q * 65536;
        int r = i >> 9, c = i & 511;
        int tr = r >> 7, tc = c >> 7, rr = r & 127, cc = c & 127;
        if (tr > tc) { int tmp = tr; tr = tc; tc = tmp; tmp = rr; rr = cc; cc = tmp; }
        int tid = tr * 4 + tc - ((tr * (tr + 1)) >> 1);
        const float* src = Gp + ((size_t)tid << 14) + rr * 128 + cc;
        float ssum = 0.f;
        #pragma unroll
        for (int p = 0; p < 16; ++p) ssum += src[(size_t)p * 163840];
        G[i] = ssum;
    }
}

// ============ P5: protos = (v + u@G) / n  -> out[0:51200) ==============
__device__ void phase_pgemm(SMem& sm, int bx, int t, const float* __restrict__ u_arr,
        const float* __restrict__ v_arr, const int* __restrict__ cnt,
        const float* __restrict__ G, float* __restrict__ out) {
    if (bx >= 2 * C_CLS) return;
    int c = bx >> 1;
    int j = ((bx & 1) << 8) + t;
    sm.ug[t]       = u_arr[(size_t)c * D_DIM + t];
    sm.ug[t + 256] = u_arr[(size_t)c * D_DIM + t + 256];
    __syncthreads();
    float acc = v_arr[(size_t)c * D_DIM + j];
    #pragma unroll 8
    for (int k = 0; k < D_DIM; ++k)
        acc += sm.ug[k] * G[(size_t)k * D_DIM + j];
    int n = cnt[c];
    float s = (n > 0) ? 1.0f / (float)n : 0.0f;
    out[(size_t)c * D_DIM + j] = acc * s;
}

// ============ P6: inter[i,j,:] = proto[j] - proto[i] ===================
__device__ void phase_inter(int bx, int t, const float* __restrict__ proto,
                            float* __restrict__ inter) {
    for (int pp = bx * 2; pp < C_CLS * C_CLS; pp += GRID * 2) {
        int pair = pp + (t >> 7);
        int i = pair / C_CLS;
        int j = pair - i * C_CLS;
        int d = (t & 127) << 2;
        float4 pj = *(const float4*)&proto[j * D_DIM + d];
        float4 pi = *(const float4*)&proto[i * D_DIM + d];
        float4 r;
        r.x = pj.x - pi.x; r.y = pj.y - pi.y; r.z = pj.z - pi.z; r.w = pj.w - pi.w;
        *(float4*)&inter[(size_t)pair * D_DIM + d] = r;
    }
}

// ================= fused cooperative mega-kernel =======================
__global__ __launch_bounds__(256, 2) void k_all(
        const float* __restrict__ x, const float* __restrict__ logits,
        float* __restrict__ wv, int* __restrict__ cls,
        float* __restrict__ inv, float* __restrict__ sinv,
        u16* __restrict__ zth, u16* __restrict__ ztl,
        int* __restrict__ cnt, int* __restrict__ offs, int* __restrict__ order,
        float* __restrict__ Gp, float* __restrict__ u_arr, float* __restrict__ v_arr,
        float* __restrict__ G, float* __restrict__ out) {
    cg::grid_group grid = cg::this_grid();
    __shared__ SMem sm;
    int bx = blockIdx.x, t = threadIdx.x;
    phase_prep(bx, t, logits, x, wv, cls, inv, sinv);
    grid.sync();
    phase_mid(sm, bx, t, x, sinv, cls, zth, ztl, cnt, offs, order);
    grid.sync();
    phase_big(sm, bx, t, zth, ztl, x, inv, wv, order, offs, cnt, Gp, u_arr, v_arr);
    grid.sync();
    phase_reduceG(bx, t, Gp, G);
    grid.sync();
    phase_pgemm(sm, bx, t, u_arr, v_arr, cnt, G, out);
    grid.sync();
    phase_inter(bx, t, out, out + C_CLS * D_DIM);
}

// ================= fallback per-phase kernels ==========================
__global__ __launch_bounds__(256) void k_p1(const float* x, const float* logits,
        float* wv, int* cls, float* inv, float* sinv) {
    phase_prep(blockIdx.x, threadIdx.x, logits, x, wv, cls, inv, sinv);
}
__global__ __launch_bounds__(256) void k_p2(const float* x, const float* sinv,
        const int* cls, u16* zth, u16* ztl, int* cnt, int* offs, int* order) {
    __shared__ SMem sm;
    phase_mid(sm, blockIdx.x, threadIdx.x, x, sinv, cls, zth, ztl, cnt, offs, order);
}
__global__ __launch_bounds__(256) void k_p3(const u16* zth, const u16* ztl,
        const float* x, const float* inv, const float* wv, const int* order,
        const int* offs, const int* cnt, float* Gp, float* u_arr, float* v_arr) {
    __shared__ SMem sm;
    phase_big(sm, blockIdx.x, threadIdx.x, zth, ztl, x, inv, wv, order, offs, cnt,
              Gp, u_arr, v_arr);
}
__global__ __launch_bounds__(256) void k_p4(const float* Gp, float* G) {
    phase_reduceG(blockIdx.x, threadIdx.x, Gp, G);
}
__global__ __launch_bounds__(256) void k_p5(const float* u_arr, const float* v_arr,
        const int* cnt, const float* G, float* out) {
    __shared__ SMem sm;
    phase_pgemm(sm, blockIdx.x, threadIdx.x, u_arr, v_arr, cnt, G, out);
}
__global__ __launch_bounds__(256) void k_p6(const float* proto, float* inter) {
    phase_inter(blockIdx.x, threadIdx.x, proto, inter);
}

extern "C" void kernel_launch(void* const* d_in, const int* in_sizes, int n_in,
                              void* d_out, int out_size, void* d_ws, size_t ws_size,
                              hipStream_t stream) {
    const float* x      = (const float*)d_in[0];   // [8192, 512]
    const float* logits = (const float*)d_in[1];   // [8192, 100]
    float* out = (float*)d_out;
    float* ws  = (float*)d_ws;
    float* G     = ws + WS_G;
    float* Gp    = ws + WS_GP;
    float* inv   = ws + WS_INV;
    float* sinv  = ws + WS_SINV;
    float* wv    = ws + WS_WV;
    int*   cls   = (int*)(ws + WS_CLS);
    int*   cnt   = (int*)(ws + WS_CNT);
    int*   offs  = (int*)(ws + WS_OFFS);
    int*   order = (int*)(ws + WS_ORDER);
    u16* zth = (u16*)(ws + WS_ZTH);
    u16* ztl = (u16*)(ws + WS_ZTL);
    float* u_arr = ws + WS_U;
    float* v_arr = ws + WS_V;

    void* args[] = {
        (void*)&x, (void*)&logits, (void*)&wv, (void*)&cls, (void*)&inv,
        (void*)&sinv, (void*)&zth, (void*)&ztl, (void*)&cnt, (void*)&offs,
        (void*)&order, (void*)&Gp, (void*)&u_arr, (void*)&v_arr, (void*)&G,
        (void*)&out
    };
    hipError_t err = hipLaunchCooperativeKernel((void*)k_all, dim3(GRID), dim3(256),
                                                args, 0, stream);
    if (err != hipSuccess) {
        // deterministic fallback: same phases as separate launches
        k_p1<<<GRID, 256, 0, stream>>>(x, logits, wv, cls, inv, sinv);
        k_p2<<<GRID, 256, 0, stream>>>(x, sinv, cls, zth, ztl, cnt, offs, order);
        k_p3<<<GRID, 256, 0, stream>>>(zth, ztl, x, inv, wv, order, offs, cnt,
                                       Gp, u_arr, v_arr);
        k_p4<<<GRID, 256, 0, stream>>>(Gp, G);
        k_p5<<<GRID, 256, 0, stream>>>(u_arr, v_arr, cnt, G, out);
        k_p6<<<GRID, 256, 0, stream>>>(out, out + C_CLS * D_DIM);
    }
}